// Round 13
// baseline (175.040 us; speedup 1.0000x reference)
//
#include <hip/hip_runtime.h>

#define SB 2048
#define DM 1024
#define N3 3072

typedef short bf16x8 __attribute__((ext_vector_type(8)));
typedef float f32x4 __attribute__((ext_vector_type(4)));
typedef unsigned short u16;

#define MFMA16(a, b, c) __builtin_amdgcn_mfma_f32_16x16x32_bf16(a, b, c, 0, 0, 0)

typedef const __attribute__((address_space(1))) unsigned int* gptr_t;
typedef __attribute__((address_space(3))) unsigned int* lptr_t;

__device__ __forceinline__ u16 f2bf(float x) {
  union { float f; unsigned u; } c; c.f = x;
  unsigned r = c.u + 0x7FFFu + ((c.u >> 16) & 1u);
  return (u16)(r >> 16);
}
__device__ __forceinline__ float bf2f(u16 x) {
  union { unsigned u; float f; } c; c.u = ((unsigned)x) << 16;
  return c.f;
}
__device__ __forceinline__ void glds(const u16* g, u16* l) {
  __builtin_amdgcn_global_load_lds((gptr_t)(const void*)g, (lptr_t)(void*)l, 16, 0, 0);
}

// slot swizzle (HW-proven 0-conflict r8-r12):
// store: row r, seg s stages global col ((s-(r>>1))&3)*8 at linear slot s
// read:  k-group kg at row r found at slot ((kg+(r>>1))&3)

// ---------------- 1) fused prep: x->bf16  |  W->Wt bf16 ----------------
__global__ void k_cvt(const float* __restrict__ x, const float* __restrict__ W,
                      u16* __restrict__ xb, u16* __restrict__ Wt) {
  int bid = blockIdx.x;
  if (bid < 8192) {
    int i = bid * 256 + threadIdx.x;                  // 8192*256 == 2097152 float4s exactly
    float4 v = ((const float4*)x)[i];
    ushort4 o;
    o.x = f2bf(v.x); o.y = f2bf(v.y); o.z = f2bf(v.z); o.w = f2bf(v.w);
    ((ushort4*)xb)[i] = o;
  } else {
    __shared__ float t[32][33];
    int wb = bid - 8192;                              // 0..3071
    int n0 = (wb % 96) * 32;
    int k0 = (wb / 96) * 32;
    int tx = threadIdx.x & 31, ty = threadIdx.x >> 5;
#pragma unroll
    for (int r = 0; r < 4; ++r)
      t[ty + r * 8][tx] = W[(size_t)(k0 + ty + r * 8) * N3 + n0 + tx];
    __syncthreads();
#pragma unroll
    for (int r = 0; r < 4; ++r)
      Wt[(size_t)(n0 + ty + r * 8) * DM + k0 + tx] = f2bf(t[tx][ty + r * 8]);
  }
}

// ---------------- 3) QKV GEMM (r12 loop + XCD L2-locality block order) ----------------
// bid -> mt=(bid&7)*8+((bid>>3)&7), nt=bid/64 : each XCD (bid%8) owns an 8-mt band
// (A-band 2MB stays L2-resident); within an XCD, 8 consecutive blocks share nt
// (B-panel reused). Bijective for 1536 = 64mt x 24nt.
__global__ __launch_bounds__(256, 2) void k_gemm(const u16* __restrict__ xb,
                                                 const u16* __restrict__ wt,
                                                 u16* __restrict__ qk,
                                                 u16* __restrict__ vt) {
  __shared__ u16 As[2][128 * 32];
  __shared__ u16 Bs[2][128 * 32];
  int bid = blockIdx.x;
  int mt = (bid & 7) * 8 + ((bid >> 3) & 7);
  int nt = bid >> 6;
  int m0 = mt * 128, n0 = nt * 128;
  int tid = threadIdx.x, lane = tid & 63, wid = tid >> 6;
  int lr = lane & 15, lg = lane >> 4;
  int wm = (wid >> 1) * 64, wn = (wid & 1) * 64;
  int ca = lane >> 2;                       // row within 16-row staging chunk
  int seg = lane & 3;                       // 16B slot within row

#define STAGE(pb, kk) do {                                                \
    _Pragma("unroll")                                                     \
    for (int j = 0; j < 2; ++j) {                                         \
      int chunk = wid * 2 + j;                                            \
      int row = chunk * 16 + ca;                                          \
      int scol = ((seg - (row >> 1)) & 3) * 8;                            \
      glds(xb + (size_t)(m0 + row) * 1024 + (kk) + scol, &As[pb][chunk * 512]); \
      glds(wt + (size_t)(n0 + row) * 1024 + (kk) + scol, &Bs[pb][chunk * 512]); \
    } } while (0)

  f32x4 acc[4][4] = {};
  int p = 0;
  STAGE(0, 0);
  __syncthreads();
  for (int t = 0; t < 32; ++t) {
    if (t < 31) STAGE(p ^ 1, t * 32 + 32);
    bf16x8 af[4], bff[4];
#pragma unroll
    for (int i = 0; i < 4; ++i) {
      int row = wm + i * 16 + lr;
      af[i] = *(const bf16x8*)&As[p][row * 32 + ((lg + (row >> 1)) & 3) * 8];
    }
#pragma unroll
    for (int j = 0; j < 4; ++j) {
      int row = wn + j * 16 + lr;
      bff[j] = *(const bf16x8*)&Bs[p][row * 32 + ((lg + (row >> 1)) & 3) * 8];
    }
#pragma unroll
    for (int i = 0; i < 4; ++i)
#pragma unroll
      for (int j = 0; j < 4; ++j)
        acc[i][j] = MFMA16(af[i], bff[j], acc[i][j]);
    __syncthreads();
    p ^= 1;
  }
#undef STAGE

  if (n0 < 2048) {
#pragma unroll
    for (int i = 0; i < 4; ++i)
#pragma unroll
      for (int j = 0; j < 4; ++j)
#pragma unroll
        for (int r = 0; r < 4; ++r)
          qk[(size_t)(m0 + wm + i * 16 + lg * 4 + r) * 2048 + n0 + wn + j * 16 + lr] = f2bf(acc[i][j][r]);
  } else {
#pragma unroll
    for (int i = 0; i < 4; ++i)
#pragma unroll
      for (int j = 0; j < 4; ++j)
#pragma unroll
        for (int r = 0; r < 4; ++r) {
          int m = m0 + wm + i * 16 + lg * 4 + r;
          int d = n0 + wn + j * 16 + lr - 2048;
          vt[(size_t)((m >> 11) * DM + d) * SB + (m & 2047)] = f2bf(acc[i][j][r]);
        }
  }
}

// ---------------- 4) S = Q K^T / 32, block-triangular (kt >= qt), bf16 ----------------
// block order: pi fast within batch -> consecutive blocks share qt (Q-panel L2 reuse)
__global__ __launch_bounds__(256, 2) void k_qkt(const u16* __restrict__ qk,
                                                u16* __restrict__ S) {
  __shared__ u16 As[2][128 * 32];
  __shared__ u16 Bs[2][128 * 32];
  int bid = blockIdx.x;
  int b = bid / 136;
  int pi = bid % 136;                // 0..135 -> (qt, kt) with kt >= qt
  int qt = 0;
  while (true) { int cnt = 16 - qt; if (pi < cnt) break; pi -= cnt; ++qt; }
  int kt = qt + pi;
  int m0 = qt * 128, n0 = kt * 128;
  int tid = threadIdx.x, lane = tid & 63, wid = tid >> 6;
  int lr = lane & 15, lg = lane >> 4;
  int wm = (wid >> 1) * 64, wn = (wid & 1) * 64;
  int ca = lane >> 2;
  int seg = lane & 3;
  const u16* Qb = qk + (size_t)(b * SB) * 2048;

#define STAGE(pb, kk) do {                                                \
    _Pragma("unroll")                                                     \
    for (int j = 0; j < 2; ++j) {                                         \
      int chunk = wid * 2 + j;                                            \
      int row = chunk * 16 + ca;                                          \
      int scol = ((seg - (row >> 1)) & 3) * 8;                            \
      glds(Qb + (size_t)(m0 + row) * 2048 + (kk) + scol, &As[pb][chunk * 512]);        \
      glds(Qb + (size_t)(n0 + row) * 2048 + 1024 + (kk) + scol, &Bs[pb][chunk * 512]); \
    } } while (0)

  f32x4 acc[4][4] = {};
  int p = 0;
  STAGE(0, 0);
  __syncthreads();
  for (int t = 0; t < 32; ++t) {
    if (t < 31) STAGE(p ^ 1, t * 32 + 32);
    bf16x8 af[4], bff[4];
#pragma unroll
    for (int i = 0; i < 4; ++i) {
      int row = wm + i * 16 + lr;
      af[i] = *(const bf16x8*)&As[p][row * 32 + ((lg + (row >> 1)) & 3) * 8];
    }
#pragma unroll
    for (int j = 0; j < 4; ++j) {
      int row = wn + j * 16 + lr;
      bff[j] = *(const bf16x8*)&Bs[p][row * 32 + ((lg + (row >> 1)) & 3) * 8];
    }
#pragma unroll
    for (int i = 0; i < 4; ++i)
#pragma unroll
      for (int j = 0; j < 4; ++j)
        acc[i][j] = MFMA16(af[i], bff[j], acc[i][j]);
    __syncthreads();
    p ^= 1;
  }
#undef STAGE

  u16* Sb = S + (size_t)(b * SB) * 2048;
#pragma unroll
  for (int i = 0; i < 4; ++i)
#pragma unroll
    for (int j = 0; j < 4; ++j)
#pragma unroll
      for (int r = 0; r < 4; ++r) {
        int q = m0 + wm + i * 16 + lg * 4 + r;
        int k = n0 + wn + j * 16 + lr;
        float v = acc[i][j][r] * 0.03125f;
        if (k < q) v = -1e30f;         // keep key >= query (anti-causal)
        Sb[(size_t)q * 2048 + k] = f2bf(v);
      }
}

// ---------------- 5) row softmax in-place on S (valid range k >= qt*128) ----------------
__global__ void k_sm(u16* __restrict__ S) {
  __shared__ float rmax[4], rsum[4];
  int row = blockIdx.x;              // b*2048 + q
  int q = row & 2047;
  int k0 = (q >> 7) << 7;
  int len = 2048 - k0;               // multiple of 128
  int tid = threadIdx.x;
  u16* rp = S + (size_t)row * 2048 + k0;
  int nv = len >> 3;
  bool act = tid < nv;
  float v[8];
  float mx = -1e30f;
  if (act) {
    bf16x8 x = *(const bf16x8*)(rp + tid * 8);
#pragma unroll
    for (int j = 0; j < 8; ++j) { v[j] = bf2f((u16)x[j]); mx = fmaxf(mx, v[j]); }
  }
#pragma unroll
  for (int off = 32; off; off >>= 1) mx = fmaxf(mx, __shfl_xor(mx, off, 64));
  int wv = tid >> 6;
  if ((tid & 63) == 0) rmax[wv] = mx;
  __syncthreads();
  mx = fmaxf(fmaxf(rmax[0], rmax[1]), fmaxf(rmax[2], rmax[3]));
  float sum = 0.f;
  if (act) {
#pragma unroll
    for (int j = 0; j < 8; ++j) { v[j] = __expf(v[j] - mx); sum += v[j]; }
  }
#pragma unroll
  for (int off = 32; off; off >>= 1) sum += __shfl_xor(sum, off, 64);
  if ((tid & 63) == 0) rsum[wv] = sum;
  __syncthreads();
  float inv = 1.f / ((rsum[0] + rsum[1]) + (rsum[2] + rsum[3]));
  if (act) {
    bf16x8 o;
#pragma unroll
    for (int j = 0; j < 8; ++j) o[j] = (short)f2bf(v[j] * inv);
    *(bf16x8*)(rp + tid * 8) = o;
  }
}

// ---------------- 6) O = P V, block-triangular variable-K, f32 out ----------------
// block order: dt fast within (qt,b) -> 8 consecutive blocks share the P-panel
__global__ __launch_bounds__(256, 2) void k_pv(const u16* __restrict__ P,
                                               const u16* __restrict__ vt,
                                               float* __restrict__ out) {
  __shared__ u16 As[2][128 * 32];
  __shared__ u16 Bs[2][128 * 32];
  int bid = blockIdx.x;
  int qt = bid >> 5;                 // heavy-first (qt=0 has longest K-loop)
  int rem = bid & 31;
  int b = rem >> 3;
  int dt = rem & 7;
  int m0 = qt * 128, n0 = dt * 128;
  int nkt = (2048 - m0) >> 5;        // K-tiles of 32
  int tid = threadIdx.x, lane = tid & 63, wid = tid >> 6;
  int lr = lane & 15, lg = lane >> 4;
  int wm = (wid >> 1) * 64, wn = (wid & 1) * 64;
  int ca = lane >> 2;
  int seg = lane & 3;
  const u16* Pb = P + (size_t)(b * SB) * 2048;
  const u16* Vb = vt + (size_t)(b * DM) * 2048;

#define STAGE(pb, kk) do {                                                \
    _Pragma("unroll")                                                     \
    for (int j = 0; j < 2; ++j) {                                         \
      int chunk = wid * 2 + j;                                            \
      int row = chunk * 16 + ca;                                          \
      int scol = ((seg - (row >> 1)) & 3) * 8;                            \
      glds(Pb + (size_t)(m0 + row) * 2048 + (kk) + scol, &As[pb][chunk * 512]); \
      glds(Vb + (size_t)(n0 + row) * 2048 + (kk) + scol, &Bs[pb][chunk * 512]); \
    } } while (0)

  f32x4 acc[4][4] = {};
  int p = 0;
  STAGE(0, m0);
  __syncthreads();
  for (int t = 0; t < nkt; ++t) {
    if (t + 1 < nkt) STAGE(p ^ 1, m0 + t * 32 + 32);
    bf16x8 af[4], bff[4];
#pragma unroll
    for (int i = 0; i < 4; ++i) {
      int row = wm + i * 16 + lr;
      af[i] = *(const bf16x8*)&As[p][row * 32 + ((lg + (row >> 1)) & 3) * 8];
    }
#pragma unroll
    for (int j = 0; j < 4; ++j) {
      int row = wn + j * 16 + lr;
      bff[j] = *(const bf16x8*)&Bs[p][row * 32 + ((lg + (row >> 1)) & 3) * 8];
    }
#pragma unroll
    for (int i = 0; i < 4; ++i)
#pragma unroll
      for (int j = 0; j < 4; ++j)
        acc[i][j] = MFMA16(af[i], bff[j], acc[i][j]);
    __syncthreads();
    p ^= 1;
  }
#undef STAGE

#pragma unroll
  for (int i = 0; i < 4; ++i)
#pragma unroll
    for (int j = 0; j < 4; ++j)
#pragma unroll
      for (int r = 0; r < 4; ++r)
        out[(size_t)(b * SB + m0 + wm + i * 16 + lg * 4 + r) * DM + n0 + wn + j * 16 + lr] = acc[i][j][r];
}

extern "C" void kernel_launch(void* const* d_in, const int* in_sizes, int n_in,
                              void* d_out, int out_size, void* d_ws, size_t ws_size,
                              hipStream_t stream) {
  const float* x = (const float*)d_in[0];
  const float* W = (const float*)d_in[1];
  float* out = (float*)d_out;
  char* ws = (char*)d_ws;
  // layout (80 MB total):
  u16* qk = (u16*)(ws);                  // 32 MB : [8192][2048] bf16 (Q | K)
  u16* vt = (u16*)(ws + 33554432);       // 16 MB : [4][1024][2048] bf16 (V^T)
  u16* xb = (u16*)(ws + 50331648);       // 16 MB : x bf16 (dead after k_gemm)
  u16* wt = (u16*)(ws + 67108864);       //  6 MB : W^T bf16 (dead after k_gemm)
  u16* S  = (u16*)(ws + 50331648);       // 32 MB : scores/P bf16, reuses xb+wt region

  k_cvt<<<11264, 256, 0, stream>>>(x, W, xb, wt);
  k_gemm<<<1536, 256, 0, stream>>>(xb, wt, qk, vt);
  k_qkt<<<544, 256, 0, stream>>>(qk, S);
  k_sm<<<8192, 256, 0, stream>>>(S);
  k_pv<<<512, 256, 0, stream>>>(S, vt, out);
}

// Round 15
// 160.827 us; speedup vs baseline: 1.0884x; 1.0884x over previous
//
#include <hip/hip_runtime.h>

#define SB 2048
#define DM 1024
#define N3 3072

typedef short bf16x8 __attribute__((ext_vector_type(8)));
typedef float f32x4 __attribute__((ext_vector_type(4)));
typedef unsigned short u16;

#define MFMA16(a, b, c) __builtin_amdgcn_mfma_f32_16x16x32_bf16(a, b, c, 0, 0, 0)

typedef const __attribute__((address_space(1))) unsigned int* gptr_t;
typedef __attribute__((address_space(3))) unsigned int* lptr_t;

__device__ __forceinline__ u16 f2bf(float x) {
  union { float f; unsigned u; } c; c.f = x;
  unsigned r = c.u + 0x7FFFu + ((c.u >> 16) & 1u);
  return (u16)(r >> 16);
}
__device__ __forceinline__ float bf2f(u16 x) {
  union { unsigned u; float f; } c; c.u = ((unsigned)x) << 16;
  return c.f;
}
__device__ __forceinline__ void glds(const u16* g, u16* l) {
  __builtin_amdgcn_global_load_lds((gptr_t)(const void*)g, (lptr_t)(void*)l, 16, 0, 0);
}

// slot swizzle (HW-proven 0-conflict r8-r13):
// store: row r, seg s stages global col ((s-(r>>1))&3)*8 at linear slot s
// read:  k-group kg at row r found at slot ((kg+(r>>1))&3)

// ---------------- 1) x fp32 -> bf16 ----------------
__global__ void k_cvt_x(const float* __restrict__ x, u16* __restrict__ xb, int n4) {
  int i = blockIdx.x * blockDim.x + threadIdx.x;
  if (i >= n4) return;
  float4 v = ((const float4*)x)[i];
  ushort4 o;
  o.x = f2bf(v.x); o.y = f2bf(v.y); o.z = f2bf(v.z); o.w = f2bf(v.w);
  ((ushort4*)xb)[i] = o;
}

// ---------------- 2) W [1024][3072] f32 -> Wt [3072][1024] bf16 ----------------
__global__ void k_cvt_wt(const float* __restrict__ W, u16* __restrict__ Wt) {
  __shared__ float t[32][33];
  int n0 = blockIdx.x * 32;
  int k0 = blockIdx.y * 32;
  int tx = threadIdx.x & 31, ty = threadIdx.x >> 5;
#pragma unroll
  for (int r = 0; r < 4; ++r)
    t[ty + r * 8][tx] = W[(size_t)(k0 + ty + r * 8) * N3 + n0 + tx];
  __syncthreads();
#pragma unroll
  for (int r = 0; r < 4; ++r)
    Wt[(size_t)(n0 + ty + r * 8) * DM + k0 + tx] = f2bf(t[tx][ty + r * 8]);
}

// ---------------- 3) QKV GEMM (r12 loop + r13's XCD L2-band mapping, FETCH-proven) ----------------
__global__ __launch_bounds__(256, 2) void k_gemm(const u16* __restrict__ xb,
                                                 const u16* __restrict__ wt,
                                                 u16* __restrict__ qk,
                                                 u16* __restrict__ vt) {
  __shared__ u16 As[2][128 * 32];
  __shared__ u16 Bs[2][128 * 32];
  int bid = blockIdx.x;
  int mt = (bid & 7) * 8 + ((bid >> 3) & 7);
  int nt = bid >> 6;
  int m0 = mt * 128, n0 = nt * 128;
  int tid = threadIdx.x, lane = tid & 63, wid = tid >> 6;
  int lr = lane & 15, lg = lane >> 4;
  int wm = (wid >> 1) * 64, wn = (wid & 1) * 64;
  int ca = lane >> 2;                       // row within 16-row staging chunk
  int seg = lane & 3;                       // 16B slot within row

#define STAGE(pb, kk) do {                                                \
    _Pragma("unroll")                                                     \
    for (int j = 0; j < 2; ++j) {                                         \
      int chunk = wid * 2 + j;                                            \
      int row = chunk * 16 + ca;                                          \
      int scol = ((seg - (row >> 1)) & 3) * 8;                            \
      glds(xb + (size_t)(m0 + row) * 1024 + (kk) + scol, &As[pb][chunk * 512]); \
      glds(wt + (size_t)(n0 + row) * 1024 + (kk) + scol, &Bs[pb][chunk * 512]); \
    } } while (0)

  f32x4 acc[4][4] = {};
  int p = 0;
  STAGE(0, 0);
  __syncthreads();
  for (int t = 0; t < 32; ++t) {
    if (t < 31) STAGE(p ^ 1, t * 32 + 32);
    bf16x8 af[4], bff[4];
#pragma unroll
    for (int i = 0; i < 4; ++i) {
      int row = wm + i * 16 + lr;
      af[i] = *(const bf16x8*)&As[p][row * 32 + ((lg + (row >> 1)) & 3) * 8];
    }
#pragma unroll
    for (int j = 0; j < 4; ++j) {
      int row = wn + j * 16 + lr;
      bff[j] = *(const bf16x8*)&Bs[p][row * 32 + ((lg + (row >> 1)) & 3) * 8];
    }
#pragma unroll
    for (int i = 0; i < 4; ++i)
#pragma unroll
      for (int j = 0; j < 4; ++j)
        acc[i][j] = MFMA16(af[i], bff[j], acc[i][j]);
    __syncthreads();
    p ^= 1;
  }
#undef STAGE

  if (n0 < 2048) {
#pragma unroll
    for (int i = 0; i < 4; ++i)
#pragma unroll
      for (int j = 0; j < 4; ++j)
#pragma unroll
        for (int r = 0; r < 4; ++r)
          qk[(size_t)(m0 + wm + i * 16 + lg * 4 + r) * 2048 + n0 + wn + j * 16 + lr] = f2bf(acc[i][j][r]);
  } else {
#pragma unroll
    for (int i = 0; i < 4; ++i)
#pragma unroll
      for (int j = 0; j < 4; ++j)
#pragma unroll
        for (int r = 0; r < 4; ++r) {
          int m = m0 + wm + i * 16 + lg * 4 + r;
          int d = n0 + wn + j * 16 + lr - 2048;
          vt[(size_t)((m >> 11) * DM + d) * SB + (m & 2047)] = f2bf(acc[i][j][r]);
        }
  }
}

// ---------------- 4) S = Q K^T / 32, block-triangular (kt >= qt), bf16 ----------------
// (r12 block order: batch fast, pi slow)
__global__ __launch_bounds__(256, 2) void k_qkt(const u16* __restrict__ qk,
                                                u16* __restrict__ S) {
  __shared__ u16 As[2][128 * 32];
  __shared__ u16 Bs[2][128 * 32];
  int bid = blockIdx.x;
  int b = bid & 3;
  int pi = bid >> 2;                 // 0..135 -> (qt, kt) with kt >= qt
  int qt = 0;
  while (true) { int cnt = 16 - qt; if (pi < cnt) break; pi -= cnt; ++qt; }
  int kt = qt + pi;
  int m0 = qt * 128, n0 = kt * 128;
  int tid = threadIdx.x, lane = tid & 63, wid = tid >> 6;
  int lr = lane & 15, lg = lane >> 4;
  int wm = (wid >> 1) * 64, wn = (wid & 1) * 64;
  int ca = lane >> 2;
  int seg = lane & 3;
  const u16* Qb = qk + (size_t)(b * SB) * 2048;

#define STAGE(pb, kk) do {                                                \
    _Pragma("unroll")                                                     \
    for (int j = 0; j < 2; ++j) {                                         \
      int chunk = wid * 2 + j;                                            \
      int row = chunk * 16 + ca;                                          \
      int scol = ((seg - (row >> 1)) & 3) * 8;                            \
      glds(Qb + (size_t)(m0 + row) * 2048 + (kk) + scol, &As[pb][chunk * 512]);        \
      glds(Qb + (size_t)(n0 + row) * 2048 + 1024 + (kk) + scol, &Bs[pb][chunk * 512]); \
    } } while (0)

  f32x4 acc[4][4] = {};
  int p = 0;
  STAGE(0, 0);
  __syncthreads();
  for (int t = 0; t < 32; ++t) {
    if (t < 31) STAGE(p ^ 1, t * 32 + 32);
    bf16x8 af[4], bff[4];
#pragma unroll
    for (int i = 0; i < 4; ++i) {
      int row = wm + i * 16 + lr;
      af[i] = *(const bf16x8*)&As[p][row * 32 + ((lg + (row >> 1)) & 3) * 8];
    }
#pragma unroll
    for (int j = 0; j < 4; ++j) {
      int row = wn + j * 16 + lr;
      bff[j] = *(const bf16x8*)&Bs[p][row * 32 + ((lg + (row >> 1)) & 3) * 8];
    }
#pragma unroll
    for (int i = 0; i < 4; ++i)
#pragma unroll
      for (int j = 0; j < 4; ++j)
        acc[i][j] = MFMA16(af[i], bff[j], acc[i][j]);
    __syncthreads();
    p ^= 1;
  }
#undef STAGE

  u16* Sb = S + (size_t)(b * SB) * 2048;
#pragma unroll
  for (int i = 0; i < 4; ++i)
#pragma unroll
    for (int j = 0; j < 4; ++j)
#pragma unroll
      for (int r = 0; r < 4; ++r) {
        int q = m0 + wm + i * 16 + lg * 4 + r;
        int k = n0 + wn + j * 16 + lr;
        float v = acc[i][j][r] * 0.03125f;
        if (k < q) v = -1e30f;         // keep key >= query (anti-causal)
        Sb[(size_t)q * 2048 + k] = f2bf(v);
      }
}

// ---------------- 5) row softmax in-place on S (valid range k >= qt*128) ----------------
__global__ void k_sm(u16* __restrict__ S) {
  __shared__ float rmax[4], rsum[4];
  int row = blockIdx.x;              // b*2048 + q
  int q = row & 2047;
  int k0 = (q >> 7) << 7;
  int len = 2048 - k0;               // multiple of 128
  int tid = threadIdx.x;
  u16* rp = S + (size_t)row * 2048 + k0;
  int nv = len >> 3;
  bool act = tid < nv;
  float v[8];
  float mx = -1e30f;
  if (act) {
    bf16x8 x = *(const bf16x8*)(rp + tid * 8);
#pragma unroll
    for (int j = 0; j < 8; ++j) { v[j] = bf2f((u16)x[j]); mx = fmaxf(mx, v[j]); }
  }
#pragma unroll
  for (int off = 32; off; off >>= 1) mx = fmaxf(mx, __shfl_xor(mx, off, 64));
  int wv = tid >> 6;
  if ((tid & 63) == 0) rmax[wv] = mx;
  __syncthreads();
  mx = fmaxf(fmaxf(rmax[0], rmax[1]), fmaxf(rmax[2], rmax[3]));
  float sum = 0.f;
  if (act) {
#pragma unroll
    for (int j = 0; j < 8; ++j) { v[j] = __expf(v[j] - mx); sum += v[j]; }
  }
#pragma unroll
  for (int off = 32; off; off >>= 1) sum += __shfl_xor(sum, off, 64);
  if ((tid & 63) == 0) rsum[wv] = sum;
  __syncthreads();
  float inv = 1.f / ((rsum[0] + rsum[1]) + (rsum[2] + rsum[3]));
  if (act) {
    bf16x8 o;
#pragma unroll
    for (int j = 0; j < 8; ++j) o[j] = (short)f2bf(v[j] * inv);
    *(bf16x8*)(rp + tid * 8) = o;
  }
}

// ---------------- 6) O = P V, block-triangular variable-K, f32 out ----------------
// (r12 block order: dt = rem>>2, b = rem&3)
__global__ __launch_bounds__(256, 2) void k_pv(const u16* __restrict__ P,
                                               const u16* __restrict__ vt,
                                               float* __restrict__ out) {
  __shared__ u16 As[2][128 * 32];
  __shared__ u16 Bs[2][128 * 32];
  int bid = blockIdx.x;
  int qt = bid >> 5;                 // heavy-first (qt=0 has longest K-loop)
  int rem = bid & 31;
  int dt = rem >> 2;
  int b = rem & 3;
  int m0 = qt * 128, n0 = dt * 128;
  int nkt = (2048 - m0) >> 5;        // K-tiles of 32
  int tid = threadIdx.x, lane = tid & 63, wid = tid >> 6;
  int lr = lane & 15, lg = lane >> 4;
  int wm = (wid >> 1) * 64, wn = (wid & 1) * 64;
  int ca = lane >> 2;
  int seg = lane & 3;
  const u16* Pb = P + (size_t)(b * SB) * 2048;
  const u16* Vb = vt + (size_t)(b * DM) * 2048;

#define STAGE(pb, kk) do {                                                \
    _Pragma("unroll")                                                     \
    for (int j = 0; j < 2; ++j) {                                         \
      int chunk = wid * 2 + j;                                            \
      int row = chunk * 16 + ca;                                          \
      int scol = ((seg - (row >> 1)) & 3) * 8;                            \
      glds(Pb + (size_t)(m0 + row) * 2048 + (kk) + scol, &As[pb][chunk * 512]); \
      glds(Vb + (size_t)(n0 + row) * 2048 + (kk) + scol, &Bs[pb][chunk * 512]); \
    } } while (0)

  f32x4 acc[4][4] = {};
  int p = 0;
  STAGE(0, m0);
  __syncthreads();
  for (int t = 0; t < nkt; ++t) {
    if (t + 1 < nkt) STAGE(p ^ 1, m0 + t * 32 + 32);
    bf16x8 af[4], bff[4];
#pragma unroll
    for (int i = 0; i < 4; ++i) {
      int row = wm + i * 16 + lr;
      af[i] = *(const bf16x8*)&As[p][row * 32 + ((lg + (row >> 1)) & 3) * 8];
    }
#pragma unroll
    for (int j = 0; j < 4; ++j) {
      int row = wn + j * 16 + lr;
      bff[j] = *(const bf16x8*)&Bs[p][row * 32 + ((lg + (row >> 1)) & 3) * 8];
    }
#pragma unroll
    for (int i = 0; i < 4; ++i)
#pragma unroll
      for (int j = 0; j < 4; ++j)
        acc[i][j] = MFMA16(af[i], bff[j], acc[i][j]);
    __syncthreads();
    p ^= 1;
  }
#undef STAGE

#pragma unroll
  for (int i = 0; i < 4; ++i)
#pragma unroll
    for (int j = 0; j < 4; ++j)
#pragma unroll
      for (int r = 0; r < 4; ++r)
        out[(size_t)(b * SB + m0 + wm + i * 16 + lg * 4 + r) * DM + n0 + wn + j * 16 + lr] = acc[i][j][r];
}

extern "C" void kernel_launch(void* const* d_in, const int* in_sizes, int n_in,
                              void* d_out, int out_size, void* d_ws, size_t ws_size,
                              hipStream_t stream) {
  const float* x = (const float*)d_in[0];
  const float* W = (const float*)d_in[1];
  float* out = (float*)d_out;
  char* ws = (char*)d_ws;
  // layout (80 MB total):
  u16* qk = (u16*)(ws);                  // 32 MB : [8192][2048] bf16 (Q | K)
  u16* vt = (u16*)(ws + 33554432);       // 16 MB : [4][1024][2048] bf16 (V^T)
  u16* xb = (u16*)(ws + 50331648);       // 16 MB : x bf16 (dead after k_gemm)
  u16* wt = (u16*)(ws + 67108864);       //  6 MB : W^T bf16 (dead after k_gemm)
  u16* S  = (u16*)(ws + 50331648);       // 32 MB : scores/P bf16, reuses xb+wt region

  k_cvt_x<<<8192, 256, 0, stream>>>(x, xb, 2097152);
  dim3 gw(96, 32);
  k_cvt_wt<<<gw, 256, 0, stream>>>(W, wt);
  k_gemm<<<1536, 256, 0, stream>>>(xb, wt, qk, vt);
  k_qkt<<<544, 256, 0, stream>>>(qk, S);
  k_sm<<<8192, 256, 0, stream>>>(S);
  k_pv<<<512, 256, 0, stream>>>(S, vt, out);
}